// Round 2
// baseline (334.316 us; speedup 1.0000x reference)
//
#include <hip/hip_runtime.h>
#include <hip/hip_bf16.h>

#define NB 4096
#define NT 50
#define NH 128
#define NINT 4

typedef float f32x4 __attribute__((ext_vector_type(4)));
typedef __bf16 bf16x8 __attribute__((ext_vector_type(8)));
typedef short short8 __attribute__((ext_vector_type(8)));

__device__ __forceinline__ unsigned short f2bf(float f) {
  unsigned int u = __float_as_uint(f);
  return (unsigned short)((u + 0x7fffu + ((u >> 16) & 1u)) >> 16);
}

__device__ __forceinline__ float sigm(float x) {
  return 1.0f / (1.0f + __expf(-x));
}
__device__ __forceinline__ float tanh_(float x) {
  return 2.0f / (1.0f + __expf(-2.0f * x)) - 1.0f;
}

// Grid: 256 blocks = NINT(4) * (NB/64)(64).  Block: 512 threads = 8 waves.
// Each block owns one interest and 64 batch rows for the whole T loop.
__global__ __launch_bounds__(512, 2)
void gru_fused(const int* __restrict__ inputs, const float* __restrict__ emb,
               const float* __restrict__ w_int, const float* __restrict__ w_ih,
               const float* __restrict__ w_hh, const float* __restrict__ b_ih,
               const float* __restrict__ b_hh, const float* __restrict__ h0,
               float* __restrict__ out) {
  __shared__ unsigned short xs[2][64 * NH];  // x tile, bf16, XOR-swizzled
  __shared__ unsigned short hs[2][64 * NH];  // h tile, bf16, XOR-swizzled
  __shared__ float gbuf[2][64];              // interest gate per row
  __shared__ float wint[4 * NH];             // w_interest, bank-swizzled
  __shared__ int idxs[NT][64];               // token ids for block rows

  const int tid = threadIdx.x;
  const int bx = blockIdx.x;
  const int I = bx >> 6;          // interest 0..3
  const int R0 = (bx & 63) * 64;  // first batch row of tile
  const int w = tid >> 6;         // wave 0..7
  const int lane = tid & 63;
  const int l15 = lane & 15;
  const int l4 = lane >> 4;
  const int col = w * 16 + l15;   // this lane's output column (0..127)

  // gather mapping: 8 threads per row
  const int gr = tid >> 3;  // row 0..63
  const int gp = tid & 7;   // part 0..7 (16 floats each)

  // ---- one-time loads: w_interest (swizzled) + token indices ----
  {
    int i = tid >> 7, k = tid & 127;
    int swz = k ^ (((k >> 4) & 3) << 2);  // spread p-strided reads over banks
    wint[i * NH + swz] = w_int[tid];
  }
  for (int q = tid; q < 64 * NT; q += 512) {
    int r = q / NT, t = q % NT;
    idxs[t][r] = inputs[(R0 + r) * NT + t];
  }
  __syncthreads();

  // ---- persistent weight fragments in registers (bf16) ----
  // B-operand of 16x16x32: lane holds col=(lane&15), k = (lane>>4)*8 + 0..7
  bf16x8 wih[3][4], whh[3][4];
  float bih[3], bhh[3];
  #pragma unroll
  for (int g = 0; g < 3; ++g) {
    int oc = g * NH + col;  // output column in [0,384)
    bih[g] = b_ih[I * 384 + oc];
    bhh[g] = b_hh[I * 384 + oc];
    #pragma unroll
    for (int kk = 0; kk < 4; ++kk) {
      int k0 = kk * 32 + l4 * 8;
      const float* pi = w_ih + ((size_t)(I * 384 + oc) * NH + k0);
      const float* ph = w_hh + ((size_t)(I * 384 + oc) * NH + k0);
      short8 si, sh;
      #pragma unroll
      for (int e = 0; e < 8; ++e) {
        si[e] = (short)f2bf(pi[e]);
        sh[e] = (short)f2bf(ph[e]);
      }
      wih[g][kk] = __builtin_bit_cast(bf16x8, si);
      whh[g][kk] = __builtin_bit_cast(bf16x8, sh);
    }
  }

  // ---- h0 master (fp32, registers) + initial bf16 LDS copy ----
  // C/D layout: col = lane&15, row = (lane>>4)*4 + reg
  float hm[4][4];
  #pragma unroll
  for (int m = 0; m < 4; ++m) {
    #pragma unroll
    for (int j = 0; j < 4; ++j) {
      int row = m * 16 + l4 * 4 + j;
      float v = h0[((size_t)I * NB + R0 + row) * NH + col];
      hm[m][j] = v;
      int e = (row * NH + col) ^ ((row & 7) << 3);
      hs[0][e] = f2bf(v);
    }
  }

  // stage gathered x into xs[buf] (bf16, swizzled) + compute gate g into gbuf[buf]
  auto stage_x = [&](int buf, const float4* v) {
    float vals[16];
    #pragma unroll
    for (int q = 0; q < 4; ++q) {
      vals[4 * q + 0] = v[q].x;
      vals[4 * q + 1] = v[q].y;
      vals[4 * q + 2] = v[q].z;
      vals[4 * q + 3] = v[q].w;
    }
    short8 s0, s1;
    #pragma unroll
    for (int e = 0; e < 8; ++e) {
      s0[e] = (short)f2bf(vals[e]);
      s1[e] = (short)f2bf(vals[8 + e]);
    }
    int base = gr * NH + gp * 16;
    int sw = (gr & 7) << 3;
    *(short8*)&xs[buf][(base) ^ sw] = s0;
    *(short8*)&xs[buf][(base + 8) ^ sw] = s1;
    // interest dots (fp32)
    float d[4] = {0.f, 0.f, 0.f, 0.f};
    #pragma unroll
    for (int e4 = 0; e4 < 4; ++e4) {
      int k0 = gp * 16 + e4 * 4;
      int swz = k0 ^ ((gp & 3) << 2);
      #pragma unroll
      for (int i = 0; i < 4; ++i) {
        float4 wv = *(const float4*)&wint[i * NH + swz];
        d[i] += vals[e4 * 4 + 0] * wv.x + vals[e4 * 4 + 1] * wv.y +
                vals[e4 * 4 + 2] * wv.z + vals[e4 * 4 + 3] * wv.w;
      }
    }
    #pragma unroll
    for (int off = 1; off < 8; off <<= 1) {
      #pragma unroll
      for (int i = 0; i < 4; ++i) d[i] += __shfl_xor(d[i], off, 64);
    }
    float sa = d[0] * 10.f, sb = d[1] * 10.f, sc = d[2] * 10.f, sd = d[3] * 10.f;
    float mx = fmaxf(fmaxf(sa, sb), fmaxf(sc, sd));
    float ea = __expf(sa - mx), eb = __expf(sb - mx), ec = __expf(sc - mx),
          ed = __expf(sd - mx);
    float sum = ea + eb + ec + ed;
    float sel = (I == 0) ? ea : (I == 1) ? eb : (I == 2) ? ec : ed;
    if (gp == 0) gbuf[buf][gr] = sel / sum;
  };

  // ---- prologue: gather x(0), gate g(0) ----
  {
    int nid = idxs[0][gr];
    const float4* src = (const float4*)(emb + (size_t)nid * NH + gp * 16);
    float4 v[4];
    #pragma unroll
    for (int q = 0; q < 4; ++q) v[q] = src[q];
    stage_x(0, v);
  }
  __syncthreads();

  // ---- main recurrence ----
  for (int t = 0; t < NT; ++t) {
    const int cur = t & 1, nxt = cur ^ 1;

    // prefetch x(t+1) early; conversion/use happens after the MFMAs
    float4 pv[4];
    const bool pf = (t + 1 < NT);
    if (pf) {
      int nid = idxs[t + 1][gr];
      const float4* src = (const float4*)(emb + (size_t)nid * NH + gp * 16);
      #pragma unroll
      for (int q = 0; q < 4; ++q) pv[q] = src[q];
    }

    const unsigned short* hsc = hs[cur];
    const unsigned short* xsc = xs[cur];
    unsigned short* hsn = hs[nxt];

    #pragma unroll
    for (int m = 0; m < 4; ++m) {
      f32x4 agi[3], agh[3];
      #pragma unroll
      for (int g = 0; g < 3; ++g) {
        agi[g] = f32x4{bih[g], bih[g], bih[g], bih[g]};
        agh[g] = f32x4{bhh[g], bhh[g], bhh[g], bhh[g]};
      }
      int arow = m * 16 + l15;
      int alin = arow * NH + l4 * 8;   // bits 3-4 from l4*8
      int sw = (arow & 7) << 3;        // bits 3-5
      #pragma unroll
      for (int kk = 0; kk < 4; ++kk) {
        // kk*32 has bits 5-6, disjoint from alin's low bits: add is carry-free;
        // XOR the FULL linear index (round-1 bug: XOR-then-add carried into bit 6)
        int e = (alin + kk * 32) ^ sw;
        bf16x8 ah = __builtin_bit_cast(bf16x8, *(const short8*)&hsc[e]);
        bf16x8 ax = __builtin_bit_cast(bf16x8, *(const short8*)&xsc[e]);
        #pragma unroll
        for (int g = 0; g < 3; ++g) {
          agh[g] = __builtin_amdgcn_mfma_f32_16x16x32_bf16(ah, whh[g][kk], agh[g], 0, 0, 0);
          agi[g] = __builtin_amdgcn_mfma_f32_16x16x32_bf16(ax, wih[g][kk], agi[g], 0, 0, 0);
        }
      }
      #pragma unroll
      for (int j = 0; j < 4; ++j) {
        int row = m * 16 + l4 * 4 + j;
        float gv = gbuf[cur][row];
        float rg = sigm(agi[0][j] + agh[0][j]);
        float ig = sigm(agi[1][j] + agh[1][j]);
        float ng = tanh_(agi[2][j] + rg * agh[2][j]);
        float c = (gv > 0.01f) ? gv * ig : 0.0f;
        float hy = (1.0f - c) * hm[m][j] + c * ng;
        hm[m][j] = hy;
        int e = (row * NH + col) ^ ((row & 7) << 3);
        hsn[e] = f2bf(hy);
      }
    }

    if (pf) stage_x(nxt, pv);
    __syncthreads();
  }

  // ---- epilogue: out[b][I][h] ----
  #pragma unroll
  for (int m = 0; m < 4; ++m) {
    #pragma unroll
    for (int j = 0; j < 4; ++j) {
      int row = m * 16 + l4 * 4 + j;
      out[(size_t)(R0 + row) * (NINT * NH) + I * NH + col] = hm[m][j];
    }
  }
}

extern "C" void kernel_launch(void* const* d_in, const int* in_sizes, int n_in,
                              void* d_out, int out_size, void* d_ws, size_t ws_size,
                              hipStream_t stream) {
  const int* inputs = (const int*)d_in[0];
  const float* emb = (const float*)d_in[1];
  const float* w_int = (const float*)d_in[2];
  const float* w_ih = (const float*)d_in[3];
  const float* w_hh = (const float*)d_in[4];
  const float* b_ih = (const float*)d_in[5];
  const float* b_hh = (const float*)d_in[6];
  const float* h0 = (const float*)d_in[7];
  float* out = (float*)d_out;

  dim3 grid(NINT * (NB / 64));  // 256 blocks, one per CU
  dim3 block(512);
  gru_fused<<<grid, block, 0, stream>>>(inputs, emb, w_int, w_ih, w_hh, b_ih,
                                        b_hh, h0, out);
}